// Round 8
// baseline (287.745 us; speedup 1.0000x reference)
//
#include <hip/hip_runtime.h>
#include <hip/hip_bf16.h>

#define B_SZ    2
#define L_SEQ   2048
#define D_MODEL 384
#define D_INNER 768
#define D_STATE 16
#define DT_RANK 24
#define ML      (B_SZ * L_SEQ)   // 4096 rows
#define NCHUNK  64
#define CHLEN   (L_SEQ / NCHUNK) // 32

typedef __hip_bfloat16 bf16;
typedef __attribute__((ext_vector_type(8))) short bf16x8;
typedef __attribute__((ext_vector_type(4))) float f32x4;
typedef __attribute__((ext_vector_type(8))) float f32x8;

__device__ __forceinline__ float bf2f(short s) {
    return __uint_as_float(((unsigned)(unsigned short)s) << 16);
}
__device__ __forceinline__ short f2bf(float f) {
    return (short)__bfloat16_as_ushort(__float2bfloat16(f));
}

// ---------------------------------------------------------------------------
// MFMA bf16 GEMM. C(MxN) = A(MxK) * W(KxN), W fp32 row-major.
// AMODE 0: A fp32 row-major [M][K] (in_proj).
// AMODE 1: A bf16 TRANSPOSED [K][M] (xp_t / y_t; stride M).
// 256 thr / 4 waves; tile 64x64, BK=64; wave = 32x32 via 2x2 16x16x32 MFMA.
// D: col=lane&15, row=(lane>>4)*4+reg  (m89/m91-verified)
// EPI 0: in_proj split, transposed: outb0[n][m]=xp_raw, outb1[n-768][m]=silu(z)
// EPI 1: outf = fp32 C row-major (ld=N, guard n<N)
// EPI 2: x_proj: n<24 -> outf[m*24+n]; n in [24,40) -> outf2[m*32+2(n-24)]=B;
//        n in [40,56) -> outf2[m*32+2(n-40)+1]=C   (interleaved fp32 pairs)
// ---------------------------------------------------------------------------
template<int EPI, int AMODE>
__global__ __launch_bounds__(256)
void gemm_mfma(const float* __restrict__ Af, const bf16* __restrict__ At,
               const float* __restrict__ W,
               bf16* __restrict__ outb0, bf16* __restrict__ outb1,
               float* __restrict__ outf, float* __restrict__ outf2,
               int M, int N, int K)
{
    __shared__ __attribute__((aligned(16))) short As[64][72];
    __shared__ __attribute__((aligned(16))) short Bs[64][72];
    const int tid  = threadIdx.x;
    const int lane = tid & 63;
    const int wave = tid >> 6;
    const int wm   = (wave & 1) * 32;
    const int wn   = (wave >> 1) * 32;
    const int m0   = blockIdx.y * 64;
    const int n0   = blockIdx.x * 64;

    f32x4 acc[2][2];
#pragma unroll
    for (int i = 0; i < 2; i++)
#pragma unroll
        for (int j = 0; j < 2; j++)
#pragma unroll
            for (int r = 0; r < 4; r++) acc[i][j][r] = 0.f;

    for (int kt = 0; kt < K; kt += 64) {
        __syncthreads();
        // Stage A tile 64x64
#pragma unroll
        for (int i = 0; i < 2; i++) {
            int c = tid + 256 * i;
            if (AMODE == 0) {                    // fp32 row-major
                int m = c >> 3, k8 = (c & 7) * 8;
                f32x8 a = *(const f32x8*)&Af[(size_t)(m0 + m) * K + kt + k8];
                bf16x8 h;
#pragma unroll
                for (int j = 0; j < 8; j++) h[j] = f2bf(a[j]);
                *(bf16x8*)&As[m][k8] = h;
            } else {                             // bf16 transposed [K][M]
                int m8 = (c & 7) * 8, k = c >> 3;
                bf16x8 a = *(const bf16x8*)&At[(size_t)(kt + k) * M + m0 + m8];
#pragma unroll
                for (int j = 0; j < 8; j++) As[m8 + j][k] = a[j];
            }
        }
        // Stage W tile 64x64 transposed into Bs[n][k], fp32 -> bf16
#pragma unroll
        for (int i = 0; i < 2; i++) {
            int c = tid + 256 * i;
            int n8 = (c & 7) * 8, k = c >> 3;
            if (n0 + n8 + 8 <= N) {
                f32x8 w = *(const f32x8*)&W[(size_t)(kt + k) * N + n0 + n8];
#pragma unroll
                for (int j = 0; j < 8; j++) Bs[n8 + j][k] = f2bf(w[j]);
            } else {
#pragma unroll
                for (int j = 0; j < 8; j++) Bs[n8 + j][k] = 0;
            }
        }
        __syncthreads();
#pragma unroll
        for (int ks = 0; ks < 2; ks++) {
            int kb = ks * 32 + (lane >> 4) * 8;
            bf16x8 a0 = *(const bf16x8*)&As[wm + (lane & 15)][kb];
            bf16x8 a1 = *(const bf16x8*)&As[wm + 16 + (lane & 15)][kb];
            bf16x8 b0 = *(const bf16x8*)&Bs[wn + (lane & 15)][kb];
            bf16x8 b1 = *(const bf16x8*)&Bs[wn + 16 + (lane & 15)][kb];
            acc[0][0] = __builtin_amdgcn_mfma_f32_16x16x32_bf16(a0, b0, acc[0][0], 0, 0, 0);
            acc[0][1] = __builtin_amdgcn_mfma_f32_16x16x32_bf16(a0, b1, acc[0][1], 0, 0, 0);
            acc[1][0] = __builtin_amdgcn_mfma_f32_16x16x32_bf16(a1, b0, acc[1][0], 0, 0, 0);
            acc[1][1] = __builtin_amdgcn_mfma_f32_16x16x32_bf16(a1, b1, acc[1][1], 0, 0, 0);
        }
    }

#pragma unroll
    for (int am = 0; am < 2; am++)
#pragma unroll
        for (int bn = 0; bn < 2; bn++)
#pragma unroll
            for (int r = 0; r < 4; r++) {
                int m = m0 + wm + am * 16 + (lane >> 4) * 4 + r;
                int n = n0 + wn + bn * 16 + (lane & 15);
                float v = acc[am][bn][r];
                if (EPI == 0) {
                    if (n < D_INNER)
                        outb0[(size_t)n * ML + m] = __float2bfloat16(v);
                    else
                        outb1[(size_t)(n - D_INNER) * ML + m] =
                            __float2bfloat16(v / (1.f + __expf(-v)));
                } else if (EPI == 1) {
                    if (n < N) outf[(size_t)m * N + n] = v;
                } else {
                    if (n < DT_RANK)
                        outf[(size_t)m * DT_RANK + n] = v;
                    else if (n < DT_RANK + D_STATE)
                        outf2[(size_t)m * 32 + 2 * (n - DT_RANK)] = v;
                    else if (n < DT_RANK + 2 * D_STATE)
                        outf2[(size_t)m * 32 + 2 * (n - DT_RANK - D_STATE) + 1] = v;
                }
            }
}

// ---------------------------------------------------------------------------
// Causal depthwise conv (K=4) + bias + SiLU, 8 outputs/thread, [d][ml] layout.
// grid = (ML/2048, D_INNER), block 256.
// ---------------------------------------------------------------------------
__global__ __launch_bounds__(256)
void conv_silu_kernel(const bf16* __restrict__ xp_raw_t,
                      const float* __restrict__ cw, const float* __restrict__ cb,
                      bf16* __restrict__ xp_t)
{
    const int ml0 = (blockIdx.x * 256 + threadIdx.x) * 8;
    const int d   = blockIdx.y;
    const int l0  = ml0 & (L_SEQ - 1);
    const size_t row = (size_t)d * ML;
    const float w0 = cw[d * 4 + 0], w1 = cw[d * 4 + 1],
                w2 = cw[d * 4 + 2], w3 = cw[d * 4 + 3], bias = cb[d];

    bf16x8 cur = *(const bf16x8*)&xp_raw_t[row + ml0];
    bf16x8 prev;
    if (ml0 != 0) prev = *(const bf16x8*)&xp_raw_t[row + ml0 - 8];
    else {
#pragma unroll
        for (int j = 0; j < 8; j++) prev[j] = 0;
    }
    float w[16];
#pragma unroll
    for (int k = 0; k < 8; k++) { w[k] = bf2f(prev[k]); w[k + 8] = bf2f(cur[k]); }

    bf16x8 out;
#pragma unroll
    for (int o = 0; o < 8; o++) {
        int l = l0 + o;
        float s = bias;
        if (l >= 3) {
            s += w0 * w[5 + o] + w1 * w[6 + o] + w2 * w[7 + o] + w3 * w[8 + o];
        } else {
            if (l - 3 >= 0) s += w0 * w[5 + o];
            if (l - 2 >= 0) s += w1 * w[6 + o];
            if (l - 1 >= 0) s += w2 * w[7 + o];
            s += w3 * w[8 + o];
        }
        out[o] = f2bf(s / (1.f + __expf(-s)));
    }
    *(bf16x8*)&xp_t[row + ml0] = out;
}

// ---------------------------------------------------------------------------
// dt = softplus(dt_r @ dt_proj_w + b), transposed output [d][m].
// grid = (ML/256, D_INNER); x_dbl24 = [m][24] fp32.
// ---------------------------------------------------------------------------
__global__ __launch_bounds__(256)
void dt_kernel(const float* __restrict__ x_dbl24, const float* __restrict__ dtw,
               const float* __restrict__ dtb, bf16* __restrict__ dt_t)
{
    const int m = blockIdx.x * 256 + threadIdx.x;
    const int d = blockIdx.y;
    float acc = dtb[d];
    const float* xr = &x_dbl24[(size_t)m * DT_RANK];
#pragma unroll
    for (int r = 0; r < DT_RANK; r++)
        acc += xr[r] * dtw[r * D_INNER + d];
    float sp = fmaxf(acc, 0.f) + log1pf(__expf(-fabsf(acc)));
    dt_t[(size_t)d * ML + m] = __float2bfloat16(sp);
}

// ---------------------------------------------------------------------------
// Chunk-parallel selective scan (recompute variant), register-preloaded.
// One 1024-thr block per (b,d); thread = (chunk c=tid>>4, state n=tid&15).
// dt/xp/zs chunk slices are 64B -> preloaded as 4x bf16x8 (broadcast over the
// 16 n-lanes), reused in both phases. B,C come from interleaved fp32 pairs
// bc[m*32+2n]=(B_n,C_n): one float2 load per step, immediate offsets.
// y accumulated in registers, 4x16B store by lane 0.
// ---------------------------------------------------------------------------
__global__ __launch_bounds__(1024)
void scan_kernel(const bf16* __restrict__ dt_t, const bf16* __restrict__ xp_t,
                 const float* __restrict__ bc, const bf16* __restrict__ zs_t,
                 const float* __restrict__ A_log, const float* __restrict__ Dp,
                 bf16* __restrict__ y_t)
{
    __shared__ float sP[NCHUNK][D_STATE];
    __shared__ float sH[NCHUNK][D_STATE];
    const int tid = threadIdx.x;
    const int c = tid >> 4;           // chunk 0..63
    const int n = tid & 15;           // state 0..15
    const int g = blockIdx.x;         // (b,d)
    const int b = g / D_INNER;
    const int d = g % D_INNER;
    const float A = -__expf(A_log[d * D_STATE + n]);
    const size_t base_t = (size_t)d * ML + (size_t)b * L_SEQ + (size_t)c * CHLEN;
    const size_t base_m = (size_t)b * L_SEQ + (size_t)c * CHLEN;
    const float2* __restrict__ bc2 =
        (const float2*)bc + base_m * (D_STATE) + n;   // row stride 16 float2

    bf16x8 vdt[4], vxp[4];
#pragma unroll
    for (int i = 0; i < 4; i++) {
        vdt[i] = *(const bf16x8*)&dt_t[base_t + 8 * i];
        vxp[i] = *(const bf16x8*)&xp_t[base_t + 8 * i];
    }

    float h = 0.f, P = 1.f;
#pragma unroll
    for (int i = 0; i < 4; i++) {
#pragma unroll
        for (int k = 0; k < 8; k++) {
            const int j = i * 8 + k;
            float dtv = bf2f(vdt[i][k]);
            float xpv = bf2f(vxp[i][k]);
            float2 bcv = bc2[j * D_STATE];
            float aj = __expf(dtv * A);
            h = aj * h + bcv.x * (dtv * xpv);
            P *= aj;
        }
    }
    sP[c][n] = P;
    sH[c][n] = h;
    __syncthreads();

    // Kogge-Stone inclusive scan over chunks: compose (P,h) pairs
#pragma unroll
    for (int s = 1; s < NCHUNK; s <<= 1) {
        float p2 = 0.f, h2 = 0.f;
        const bool act = (c >= s);
        if (act) { p2 = sP[c - s][n]; h2 = sH[c - s][n]; }
        __syncthreads();
        if (act) {
            sH[c][n] = sP[c][n] * h2 + sH[c][n];
            sP[c][n] = sP[c][n] * p2;
        }
        __syncthreads();
    }
    const float hinit = (c == 0) ? 0.f : sH[c - 1][n];

    // Phase 3: corrected re-scan + output (all lanes compute, lane 0 stores)
    const float Dd = Dp[d];
    h = hinit;
    bf16x8 vy[4];
#pragma unroll
    for (int i = 0; i < 4; i++) {
        bf16x8 vzs = *(const bf16x8*)&zs_t[base_t + 8 * i];
#pragma unroll
        for (int k = 0; k < 8; k++) {
            const int j = i * 8 + k;
            float dtv = bf2f(vdt[i][k]);
            float xpv = bf2f(vxp[i][k]);
            float2 bcv = bc2[j * D_STATE];
            float aj = __expf(dtv * A);
            h = aj * h + bcv.x * (dtv * xpv);
            float yv = h * bcv.y;
            yv += __shfl_xor(yv, 1);
            yv += __shfl_xor(yv, 2);
            yv += __shfl_xor(yv, 4);
            yv += __shfl_xor(yv, 8);
            vy[i][k] = f2bf((yv + xpv * Dd) * bf2f(vzs[k]));
        }
    }
    if (n == 0) {
#pragma unroll
        for (int i = 0; i < 4; i++)
            *(bf16x8*)&y_t[base_t + 8 * i] = vy[i];
    }
}

// ---------------------------------------------------------------------------
extern "C" void kernel_launch(void* const* d_in, const int* in_sizes, int n_in,
                              void* d_out, int out_size, void* d_ws, size_t ws_size,
                              hipStream_t stream)
{
    const float* x         = (const float*)d_in[0];
    const float* in_proj_w = (const float*)d_in[1];
    const float* conv_w    = (const float*)d_in[2];
    const float* conv_b    = (const float*)d_in[3];
    const float* x_proj_w  = (const float*)d_in[4];
    const float* dt_proj_w = (const float*)d_in[5];
    const float* dt_proj_b = (const float*)d_in[6];
    const float* A_log     = (const float*)d_in[7];
    const float* Dvec      = (const float*)d_in[8];
    const float* out_proj_w= (const float*)d_in[9];

    // workspace: 4x bf16 [768][ML] + fp32 x_dbl24 [ML][24] + fp32 bc [ML][32]
    bf16* xp_raw_t = (bf16*)d_ws;                        // (reused as y_t)
    bf16* zs_t     = xp_raw_t + (size_t)ML * D_INNER;
    bf16* xp_t     = zs_t     + (size_t)ML * D_INNER;
    bf16* dt_t     = xp_t     + (size_t)ML * D_INNER;
    float* x_dbl24 = (float*)(dt_t + (size_t)ML * D_INNER);
    float* bc      = x_dbl24 + (size_t)ML * DT_RANK;
    bf16* y_t      = xp_raw_t;                           // alias (dead after conv)

    dim3 blk(256);

    // 1) in_proj -> xp_raw_t | zs_t (transposed bf16)
    gemm_mfma<0, 0><<<dim3(2 * D_INNER / 64, ML / 64), blk, 0, stream>>>(
        x, nullptr, in_proj_w, xp_raw_t, zs_t, nullptr, nullptr,
        ML, 2 * D_INNER, D_MODEL);

    // 2) depthwise causal conv + silu (8 outputs/thread)
    conv_silu_kernel<<<dim3(ML / 2048, D_INNER), blk, 0, stream>>>(
        xp_raw_t, conv_w, conv_b, xp_t);

    // 3) x_proj -> x_dbl24 (dt_r fp32) + bc (B,C interleaved fp32 pairs)
    gemm_mfma<2, 1><<<dim3(1, ML / 64), blk, 0, stream>>>(
        nullptr, xp_t, x_proj_w, nullptr, nullptr, x_dbl24, bc,
        ML, DT_RANK + 2 * D_STATE, D_INNER);

    // 4) dt_proj + softplus -> dt_t
    dt_kernel<<<dim3(ML / 256, D_INNER), blk, 0, stream>>>(
        x_dbl24, dt_proj_w, dt_proj_b, dt_t);

    // 5) chunk-parallel selective scan -> y_t (aliases xp_raw_t)
    scan_kernel<<<B_SZ * D_INNER, 1024, 0, stream>>>(
        dt_t, xp_t, bc, zs_t, A_log, Dvec, y_t);

    // 6) out_proj -> d_out fp32
    gemm_mfma<1, 1><<<dim3(D_MODEL / 64, ML / 64), blk, 0, stream>>>(
        nullptr, y_t, out_proj_w, nullptr, nullptr, (float*)d_out, nullptr,
        ML, D_MODEL, D_INNER);
}

// Round 12
// 274.255 us; speedup vs baseline: 1.0492x; 1.0492x over previous
//
#include <hip/hip_runtime.h>
#include <hip/hip_bf16.h>

#define B_SZ    2
#define L_SEQ   2048
#define D_MODEL 384
#define D_INNER 768
#define D_STATE 16
#define DT_RANK 24
#define ML      (B_SZ * L_SEQ)   // 4096 rows
#define NCHUNK  64
#define CHLEN   (L_SEQ / NCHUNK) // 32

typedef __hip_bfloat16 bf16;
typedef __attribute__((ext_vector_type(8))) short bf16x8;
typedef __attribute__((ext_vector_type(4))) float f32x4;
typedef __attribute__((ext_vector_type(8))) float f32x8;

// ---------------------------------------------------------------------------
// MFMA bf16 GEMM. C(MxN) = A(MxK) * W(KxN), W fp32 row-major.
// AMODE 0: A fp32 row-major [M][K] (in_proj).
// AMODE 1: A bf16 TRANSPOSED [K][M] (xp_t / y_t; stride M).
// 256 thr / 4 waves; tile 64x64, BK=64; wave = 32x32 via 2x2 16x16x32 MFMA.
// A-frag: A[m=lane&15][k=(lane>>4)*8+j]; B-frag: B[n=lane&15][k=...]
// D: col=lane&15, row=(lane>>4)*4+reg  (m89/m91-verified)
// EPI 0: in_proj split, TRANSPOSED outputs: outb0[n][m]=xp_raw (n<768),
//        outb1[n-768][m]=silu(z)  (both bf16, stride ML)
// EPI 1: outf = fp32 C row-major (ld=N, guard n<N)
// ---------------------------------------------------------------------------
template<int EPI, int AMODE>
__global__ __launch_bounds__(256)
void gemm_mfma(const float* __restrict__ Af, const bf16* __restrict__ At,
               const float* __restrict__ W,
               bf16* __restrict__ outb0, bf16* __restrict__ outb1,
               float* __restrict__ outf, int M, int N, int K)
{
    __shared__ __attribute__((aligned(16))) short As[64][72];
    __shared__ __attribute__((aligned(16))) short Bs[64][72];
    const int tid  = threadIdx.x;
    const int lane = tid & 63;
    const int wave = tid >> 6;
    const int wm   = (wave & 1) * 32;
    const int wn   = (wave >> 1) * 32;
    const int m0   = blockIdx.y * 64;
    const int n0   = blockIdx.x * 64;

    f32x4 acc[2][2];
#pragma unroll
    for (int i = 0; i < 2; i++)
#pragma unroll
        for (int j = 0; j < 2; j++)
#pragma unroll
            for (int r = 0; r < 4; r++) acc[i][j][r] = 0.f;

    for (int kt = 0; kt < K; kt += 64) {
        __syncthreads();
        // Stage A tile 64x64
#pragma unroll
        for (int i = 0; i < 2; i++) {
            int c = tid + 256 * i;
            if (AMODE == 0) {                    // fp32 row-major
                int m = c >> 3, k8 = (c & 7) * 8;
                f32x8 a = *(const f32x8*)&Af[(size_t)(m0 + m) * K + kt + k8];
                bf16x8 h;
#pragma unroll
                for (int j = 0; j < 8; j++)
                    h[j] = (short)__bfloat16_as_ushort(__float2bfloat16(a[j]));
                *(bf16x8*)&As[m][k8] = h;
            } else {                             // bf16 transposed [K][M]
                int m8 = (c & 7) * 8, k = c >> 3;
                bf16x8 a = *(const bf16x8*)&At[(size_t)(kt + k) * M + m0 + m8];
#pragma unroll
                for (int j = 0; j < 8; j++) As[m8 + j][k] = a[j];
            }
        }
        // Stage W tile 64x64 transposed into Bs[n][k], fp32 -> bf16
#pragma unroll
        for (int i = 0; i < 2; i++) {
            int c = tid + 256 * i;
            int n8 = (c & 7) * 8, k = c >> 3;
            if (n0 + n8 + 8 <= N) {
                f32x8 w = *(const f32x8*)&W[(size_t)(kt + k) * N + n0 + n8];
#pragma unroll
                for (int j = 0; j < 8; j++)
                    Bs[n8 + j][k] = (short)__bfloat16_as_ushort(__float2bfloat16(w[j]));
            } else {
#pragma unroll
                for (int j = 0; j < 8; j++) Bs[n8 + j][k] = 0;
            }
        }
        __syncthreads();
#pragma unroll
        for (int ks = 0; ks < 2; ks++) {
            int kb = ks * 32 + (lane >> 4) * 8;
            bf16x8 a0 = *(const bf16x8*)&As[wm + (lane & 15)][kb];
            bf16x8 a1 = *(const bf16x8*)&As[wm + 16 + (lane & 15)][kb];
            bf16x8 b0 = *(const bf16x8*)&Bs[wn + (lane & 15)][kb];
            bf16x8 b1 = *(const bf16x8*)&Bs[wn + 16 + (lane & 15)][kb];
            acc[0][0] = __builtin_amdgcn_mfma_f32_16x16x32_bf16(a0, b0, acc[0][0], 0, 0, 0);
            acc[0][1] = __builtin_amdgcn_mfma_f32_16x16x32_bf16(a0, b1, acc[0][1], 0, 0, 0);
            acc[1][0] = __builtin_amdgcn_mfma_f32_16x16x32_bf16(a1, b0, acc[1][0], 0, 0, 0);
            acc[1][1] = __builtin_amdgcn_mfma_f32_16x16x32_bf16(a1, b1, acc[1][1], 0, 0, 0);
        }
    }

#pragma unroll
    for (int am = 0; am < 2; am++)
#pragma unroll
        for (int bn = 0; bn < 2; bn++)
#pragma unroll
            for (int r = 0; r < 4; r++) {
                int m = m0 + wm + am * 16 + (lane >> 4) * 4 + r;
                int n = n0 + wn + bn * 16 + (lane & 15);
                float v = acc[am][bn][r];
                if (EPI == 0) {
                    // transposed stores: block covers 64 consecutive m at
                    // fixed n -> full 64B lines, no write inflation
                    if (n < D_INNER)
                        outb0[(size_t)n * ML + m] = __float2bfloat16(v);
                    else
                        outb1[(size_t)(n - D_INNER) * ML + m] =
                            __float2bfloat16(v / (1.f + __expf(-v)));
                } else {
                    if (n < N) outf[(size_t)m * N + n] = v;
                }
            }
}

// ---------------------------------------------------------------------------
// Causal depthwise conv (K=4) + bias + SiLU on TRANSPOSED layout [d][ml]:
// contiguous 1-D stencil along ml. grid = (ML/256, D_INNER).
// ---------------------------------------------------------------------------
__global__ __launch_bounds__(256)
void conv_silu_kernel(const bf16* __restrict__ xp_raw_t,
                      const float* __restrict__ cw, const float* __restrict__ cb,
                      bf16* __restrict__ xp_t)
{
    const int ml = blockIdx.x * 256 + threadIdx.x;
    const int d  = blockIdx.y;
    const int l  = ml & (L_SEQ - 1);
    const size_t row = (size_t)d * ML;
    float s = cb[d];
#pragma unroll
    for (int j = 0; j < 4; j++) {
        if (l - 3 + j >= 0)
            s += __bfloat162float(xp_raw_t[row + ml - 3 + j]) * cw[d * 4 + j];
    }
    float act = s / (1.f + __expf(-s));                 // silu
    xp_t[row + ml] = __float2bfloat16(act);
}

// ---------------------------------------------------------------------------
// dt = softplus(dt_r @ dt_proj_w + b), transposed output [d][m].
// grid = (ML/256, D_INNER); dtw[r*768+d] is wave-uniform (scalar broadcast).
// ---------------------------------------------------------------------------
__global__ __launch_bounds__(256)
void dt_kernel(const float* __restrict__ x_dbl, const float* __restrict__ dtw,
               const float* __restrict__ dtb, bf16* __restrict__ dt_t)
{
    const int m = blockIdx.x * 256 + threadIdx.x;
    const int d = blockIdx.y;
    float acc = dtb[d];
    const float* xr = &x_dbl[(size_t)m * 56];
#pragma unroll
    for (int r = 0; r < DT_RANK; r++)
        acc += xr[r] * dtw[r * D_INNER + d];
    float sp = fmaxf(acc, 0.f) + log1pf(__expf(-fabsf(acc)));
    dt_t[(size_t)d * ML + m] = __float2bfloat16(sp);
}

// ---------------------------------------------------------------------------
// Chunk-parallel selective scan (recompute variant), TRANSPOSED streams.
// One 1024-thr block per (b,d); thread = (chunk c=tid>>4, state n=tid&15).
// dt_t/xp_t/zs_t/y_t rows are contiguous 4KB per (b,d) -> no line replication
// (R6: column-strided reads caused 124 MB HBM fetch via per-XCD replication).
// ---------------------------------------------------------------------------
__global__ __launch_bounds__(1024)
void scan_kernel(const bf16* __restrict__ dt_t, const bf16* __restrict__ xp_t,
                 const float* __restrict__ x_dbl, const bf16* __restrict__ zs_t,
                 const float* __restrict__ A_log, const float* __restrict__ Dp,
                 bf16* __restrict__ y_t)
{
    __shared__ float sP[NCHUNK][D_STATE];
    __shared__ float sH[NCHUNK][D_STATE];
    const int tid = threadIdx.x;
    const int c = tid >> 4;           // chunk 0..63
    const int n = tid & 15;           // state 0..15
    const int g = blockIdx.x;         // (b,d)
    const int b = g / D_INNER;
    const int d = g % D_INNER;
    const float A = -__expf(A_log[d * D_STATE + n]);
    const size_t base_t = (size_t)d * ML + (size_t)b * L_SEQ + (size_t)c * CHLEN;
    const size_t base_m = (size_t)b * L_SEQ + (size_t)c * CHLEN;

    float h = 0.f, P = 1.f;
#pragma unroll 4
    for (int j = 0; j < CHLEN; j++) {
        float dtv = __bfloat162float(dt_t[base_t + j]);
        float xpv = __bfloat162float(xp_t[base_t + j]);
        float Bn  = x_dbl[(base_m + j) * 56 + DT_RANK + n];
        float aj = __expf(dtv * A);
        float uj = Bn * (dtv * xpv);
        h = aj * h + uj;
        P *= aj;
    }
    sP[c][n] = P;
    sH[c][n] = h;
    __syncthreads();

    // Kogge-Stone inclusive scan over chunks: compose (P,h) pairs
#pragma unroll
    for (int s = 1; s < NCHUNK; s <<= 1) {
        float p2 = 0.f, h2 = 0.f;
        const bool act = (c >= s);
        if (act) { p2 = sP[c - s][n]; h2 = sH[c - s][n]; }
        __syncthreads();
        if (act) {
            sH[c][n] = sP[c][n] * h2 + sH[c][n];
            sP[c][n] = sP[c][n] * p2;
        }
        __syncthreads();
    }
    const float hinit = (c == 0) ? 0.f : sH[c - 1][n];

    // Phase 3: corrected re-scan (recompute a,u) + output
    const float Dd = Dp[d];
    h = hinit;
#pragma unroll 4
    for (int j = 0; j < CHLEN; j++) {
        float dtv = __bfloat162float(dt_t[base_t + j]);
        float xpv = __bfloat162float(xp_t[base_t + j]);
        float Bn  = x_dbl[(base_m + j) * 56 + DT_RANK + n];
        float aj = __expf(dtv * A);
        float uj = Bn * (dtv * xpv);
        h = aj * h + uj;
        float Cn = x_dbl[(base_m + j) * 56 + DT_RANK + D_STATE + n];
        float yv = h * Cn;
        yv += __shfl_xor(yv, 1);
        yv += __shfl_xor(yv, 2);
        yv += __shfl_xor(yv, 4);
        yv += __shfl_xor(yv, 8);
        if (n == 0) {
            float y = (yv + xpv * Dd) * __bfloat162float(zs_t[base_t + j]);
            y_t[base_t + j] = __float2bfloat16(y);
        }
    }
}

// ---------------------------------------------------------------------------
extern "C" void kernel_launch(void* const* d_in, const int* in_sizes, int n_in,
                              void* d_out, int out_size, void* d_ws, size_t ws_size,
                              hipStream_t stream)
{
    const float* x         = (const float*)d_in[0];
    const float* in_proj_w = (const float*)d_in[1];
    const float* conv_w    = (const float*)d_in[2];
    const float* conv_b    = (const float*)d_in[3];
    const float* x_proj_w  = (const float*)d_in[4];
    const float* dt_proj_w = (const float*)d_in[5];
    const float* dt_proj_b = (const float*)d_in[6];
    const float* A_log     = (const float*)d_in[7];
    const float* Dvec      = (const float*)d_in[8];
    const float* out_proj_w= (const float*)d_in[9];

    // workspace (all transposed [d][ml] bf16 except x_dbl): ~26.1 MB
    bf16* xp_raw_t = (bf16*)d_ws;                        // [768][ML] (reused as y_t)
    bf16* zs_t     = xp_raw_t + (size_t)ML * D_INNER;    // [768][ML] silu(z)
    bf16* xp_t     = zs_t     + (size_t)ML * D_INNER;    // [768][ML]
    bf16* dt_t     = xp_t     + (size_t)ML * D_INNER;    // [768][ML]
    float* x_dbl   = (float*)(dt_t + (size_t)ML * D_INNER); // [ML][56] fp32
    bf16* y_t      = xp_raw_t;                           // alias (dead after conv)

    dim3 blk(256);

    // 1) in_proj: (4096x384 f32)*(384x1536 f32) -> xp_raw_t | zs_t (transposed)
    gemm_mfma<0, 0><<<dim3(2 * D_INNER / 64, ML / 64), blk, 0, stream>>>(
        x, nullptr, in_proj_w, xp_raw_t, zs_t, nullptr, ML, 2 * D_INNER, D_MODEL);

    // 2) depthwise causal conv + silu (contiguous stencil in [d][ml])
    conv_silu_kernel<<<dim3(ML / 256, D_INNER), blk, 0, stream>>>(
        xp_raw_t, conv_w, conv_b, xp_t);

    // 3) x_proj: A = xp_t (transposed), W (768x56) -> x_dbl fp32 row-major
    gemm_mfma<1, 1><<<dim3(1, ML / 64), blk, 0, stream>>>(
        nullptr, xp_t, x_proj_w, nullptr, nullptr, x_dbl, ML, 56, D_INNER);

    // 4) dt_proj + softplus -> dt_t (transposed)
    dt_kernel<<<dim3(ML / 256, D_INNER), blk, 0, stream>>>(
        x_dbl, dt_proj_w, dt_proj_b, dt_t);

    // 5) chunk-parallel selective scan -> y_t (transposed, aliases xp_raw_t)
    scan_kernel<<<B_SZ * D_INNER, 1024, 0, stream>>>(
        dt_t, xp_t, x_dbl, zs_t, A_log, Dvec, y_t);

    // 6) out_proj: A = y_t (transposed), W (768x384) -> d_out fp32 row-major
    gemm_mfma<1, 1><<<dim3(D_MODEL / 64, ML / 64), blk, 0, stream>>>(
        nullptr, y_t, out_proj_w, nullptr, nullptr, (float*)d_out, ML, D_MODEL, D_INNER);
}